// Round 8
// baseline (1076.263 us; speedup 1.0000x reference)
//
#include <hip/hip_runtime.h>

// RNN B=256 T=2048 I=64 H=256 — one workgroup per sample, MFMA matvec recurrence.
// Wall = max len (2048) x per-step critical path. R6 (fully-unrolled 32-step
// block, xp in regs) = 920us = 1078cy/step; pipes sum to ~50% -> stall-bound.
// R7 trims the serial path (resubmission — previous bench died to container
// acquisition failure, no kernel evidence):
//  1. custom step barrier: s_waitcnt lgkmcnt(0) + s_barrier (no vmcnt(0) drain
//     -> block's x prefetch stays in flight across step barriers; compiler
//     still waits vmcnt at the actual use in step 31's writeback).
//  2. 8 MFMA chains depth 2 (chain j covers kt {j, j+4}); was 4 chains depth 4.
//  3. x writeback hoisted before extraction (independent of MFMA results).
// Kept: 8 waves/2-per-SIMD (measured TLP optimum 1195/982/1150 @ 1/2/4 w/SIMD),
// xp mini-GEMM per 32-step block, xp row preloaded to 8 f32x4 regs, rcp-tanh,
// no setprio (R3: overhead). Spill canary: WRITE_SIZE must stay ~11KB.

static constexpr int nB = 256;
static constexpr int nT = 2048;
static constexpr int nI = 64;
static constexpr int nH = 256;
static constexpr int XBLK = 32;     // timesteps of x staged/projected per block
static constexpr int XSTR = 72;     // halfword stride of an xbuf row
static constexpr int XPS  = 36;     // float stride of an xp row (144B: 16B-aligned)
static constexpr int THREADS = 512; // 8 waves; wave w owns output rows [32w,32w+32)

typedef _Float16 f16x8 __attribute__((ext_vector_type(8)));
typedef _Float16 f16x4 __attribute__((ext_vector_type(4)));
typedef float f32x4 __attribute__((ext_vector_type(4)));

__device__ __forceinline__ float fast_tanh(float x) {
  float a = fabsf(x);
  float e = __expf(-2.0f * a);           // in (0,1], never overflows
  float r = (1.0f - e) * __builtin_amdgcn_rcpf(1.0f + e);
  return copysignf(r, x);
}

// Step barrier: LDS-only drain. The h ds_write must be visible (lgkmcnt(0));
// each wave's own ds_reads are also lgkm ops, so cross-parity WAR is ordered.
// Deliberately NO vmcnt wait: the global x prefetch stays in flight; the
// compiler inserts its own vmcnt wait at the writeback use.
__device__ __forceinline__ void step_barrier() {
  asm volatile("s_waitcnt lgkmcnt(0)\n\ts_barrier" ::: "memory");
}

__global__ __launch_bounds__(THREADS, 2)
void rnn_mfma(const float* __restrict__ x, const int* __restrict__ lengths,
              const float* __restrict__ Wih, const float* __restrict__ Whh,
              const float* __restrict__ bih, const float* __restrict__ bhh,
              const float* __restrict__ Wfc, const float* __restrict__ bfc,
              float* __restrict__ out)
{
  __shared__ __align__(16) _Float16 hbuf[2][nH];            // 1 KB
  __shared__ __align__(16) _Float16 xbuf[2][XBLK * XSTR];   // 9 KB
  __shared__ __align__(16) float xp[nH * XPS];              // 36 KB
  __shared__ float red[THREADS / 64];

  const int b   = blockIdx.x;
  const int tid = threadIdx.x;
  const int w   = tid >> 6;       // wave 0..7
  const int l   = tid & 63;
  const int q   = l >> 4;         // quad 0..3
  const int n   = l & 15;         // MFMA column lane
  const int len = lengths[b];     // in [1, nT]
  const float* xb = x + (size_t)b * nT * nI;

  // ---- preamble: pack this wave's W rows into A-fragments (f16)
  // A layout (16x16x32): lane holds A[m = lane&15][k = 8*(lane>>4) + j], j=0..7
  f16x8 Ah[2][8];   // W_hh rows 32w+16mt+n, k = 32kt+8q+j
  f16x8 Ax[2][2];   // W_ih (I=64 -> 2 k-tiles), mini-GEMM only
#pragma unroll
  for (int mt = 0; mt < 2; ++mt) {
    const int row = 32 * w + 16 * mt + n;
#pragma unroll
    for (int kt = 0; kt < 8; ++kt) {
      const float* src = Whh + row * nH + 32 * kt + 8 * q;
      f16x8 a;
#pragma unroll
      for (int j = 0; j < 8; ++j) a[j] = (_Float16)src[j];
      Ah[mt][kt] = a;
    }
#pragma unroll
    for (int kt = 0; kt < 2; ++kt) {
      const float* src = Wih + row * nI + 32 * kt + 8 * q;
      f16x8 a;
#pragma unroll
      for (int j = 0; j < 8; ++j) a[j] = (_Float16)src[j];
      Ax[mt][kt] = a;
    }
  }
  // bias in C layout: reg r <-> row 32w + 16mt + 4q + r (folded into xp)
  f32x4 biasC[2];
#pragma unroll
  for (int r = 0; r < 4; ++r) {
    const int r0 = 32 * w + 4 * q + r;
    biasC[0][r] = bih[r0] + bhh[r0];
    biasC[1][r] = bih[r0 + 16] + bhh[r0 + 16];
  }
  // column-split ownership: lanes n<8 each finish exactly one output row
  const int mt_sel  = (n >> 2) & 1;
  const int reg_sel = n & 3;
  const int row_own = 32 * w + 16 * mt_sel + 4 * q + reg_sel;

  // x staging geometry: thread writes 4 halfs at (row, col) of the block
  const int xoff = ((tid * 4) >> 6) * XSTR + ((tid * 4) & 63);

  // ---- h0 = 0; stage x block 0
  if (tid < nH) hbuf[0][tid] = (_Float16)0.f;
  {
    float4 v = *(const float4*)(xb + tid * 4);
    f16x4 pv = { (_Float16)v.x, (_Float16)v.y, (_Float16)v.z, (_Float16)v.w };
    *(f16x4*)(xbuf[0] + xoff) = pv;
  }
  __syncthreads();

  int t = 0;
  for (int blk = 0; t < len; ++blk) {
    // ---- xp mini-GEMM: xp[row][s] = bias + W_ih . x_{blk*32+s}; timesteps
    // are the MFMA columns (ct=0 -> s=n, ct=1 -> s=16+n).
    {
      const _Float16* xB = xbuf[blk & 1];
      f32x4 g00 = biasC[0], g01 = biasC[0], g10 = biasC[1], g11 = biasC[1];
#pragma unroll
      for (int kt = 0; kt < 2; ++kt) {
        f16x8 B0 = *(const f16x8*)(xB + n * XSTR + 32 * kt + 8 * q);         // ct=0
        f16x8 B1 = *(const f16x8*)(xB + (16 + n) * XSTR + 32 * kt + 8 * q);  // ct=1
        g00 = __builtin_amdgcn_mfma_f32_16x16x32_f16(Ax[0][kt], B0, g00, 0, 0, 0);
        g10 = __builtin_amdgcn_mfma_f32_16x16x32_f16(Ax[1][kt], B0, g10, 0, 0, 0);
        g01 = __builtin_amdgcn_mfma_f32_16x16x32_f16(Ax[0][kt], B1, g01, 0, 0, 0);
        g11 = __builtin_amdgcn_mfma_f32_16x16x32_f16(Ax[1][kt], B1, g11, 0, 0, 0);
      }
#pragma unroll
      for (int r = 0; r < 4; ++r) {
        const int r0 = (32 * w + 4 * q + r) * XPS;
        xp[r0 + n]                 = g00[r];
        xp[r0 + 16 * XPS + n]      = g10[r];
        xp[r0 + 16 + n]            = g01[r];
        xp[r0 + 16 * XPS + 16 + n] = g11[r];
      }
    }
    __syncthreads();   // no vmem outstanding here (prefetch consumed at s=31)

    // next-block x prefetch (stays in flight across step barriers now),
    // then this lane's xp row -> 8 f32x4 registers.
    float4 pre;
    const bool havepre = ((blk + 1) * XBLK < len);
    if (havepre)
      pre = *(const float4*)(xb + (size_t)(blk + 1) * XBLK * nI + tid * 4);

    f32x4 xr[8];
#pragma unroll
    for (int k = 0; k < 8; ++k)
      xr[k] = *(const f32x4*)(xp + row_own * XPS + 4 * k);

    const int nsteps = min(XBLK, len - blk * XBLK);

    // step body: 8 ds_read_b128, 16 MFMA in 8 depth-2 chains, extract+tanh+write
    auto step = [&](float xpv, const _Float16* hsrc, _Float16* hdst, bool wb) {
      f32x4 z = {0.f, 0.f, 0.f, 0.f};
      f32x4 c00 = z, c01 = z, c02 = z, c03 = z;   // m-tile 0, chain j: kt {j, j+4}
      f32x4 c10 = z, c11 = z, c12 = z, c13 = z;   // m-tile 1
      f16x8 B0 = *(const f16x8*)(hsrc +   0 + 8 * q);
      f16x8 B1 = *(const f16x8*)(hsrc +  32 + 8 * q);
      f16x8 B2 = *(const f16x8*)(hsrc +  64 + 8 * q);
      f16x8 B3 = *(const f16x8*)(hsrc +  96 + 8 * q);
      f16x8 B4 = *(const f16x8*)(hsrc + 128 + 8 * q);
      f16x8 B5 = *(const f16x8*)(hsrc + 160 + 8 * q);
      f16x8 B6 = *(const f16x8*)(hsrc + 192 + 8 * q);
      f16x8 B7 = *(const f16x8*)(hsrc + 224 + 8 * q);
      c00 = __builtin_amdgcn_mfma_f32_16x16x32_f16(Ah[0][0], B0, c00, 0, 0, 0);
      c10 = __builtin_amdgcn_mfma_f32_16x16x32_f16(Ah[1][0], B0, c10, 0, 0, 0);
      c01 = __builtin_amdgcn_mfma_f32_16x16x32_f16(Ah[0][1], B1, c01, 0, 0, 0);
      c11 = __builtin_amdgcn_mfma_f32_16x16x32_f16(Ah[1][1], B1, c11, 0, 0, 0);
      c02 = __builtin_amdgcn_mfma_f32_16x16x32_f16(Ah[0][2], B2, c02, 0, 0, 0);
      c12 = __builtin_amdgcn_mfma_f32_16x16x32_f16(Ah[1][2], B2, c12, 0, 0, 0);
      c03 = __builtin_amdgcn_mfma_f32_16x16x32_f16(Ah[0][3], B3, c03, 0, 0, 0);
      c13 = __builtin_amdgcn_mfma_f32_16x16x32_f16(Ah[1][3], B3, c13, 0, 0, 0);
      c00 = __builtin_amdgcn_mfma_f32_16x16x32_f16(Ah[0][4], B4, c00, 0, 0, 0);
      c10 = __builtin_amdgcn_mfma_f32_16x16x32_f16(Ah[1][4], B4, c10, 0, 0, 0);
      c01 = __builtin_amdgcn_mfma_f32_16x16x32_f16(Ah[0][5], B5, c01, 0, 0, 0);
      c11 = __builtin_amdgcn_mfma_f32_16x16x32_f16(Ah[1][5], B5, c11, 0, 0, 0);
      c02 = __builtin_amdgcn_mfma_f32_16x16x32_f16(Ah[0][6], B6, c02, 0, 0, 0);
      c12 = __builtin_amdgcn_mfma_f32_16x16x32_f16(Ah[1][6], B6, c12, 0, 0, 0);
      c03 = __builtin_amdgcn_mfma_f32_16x16x32_f16(Ah[0][7], B7, c03, 0, 0, 0);
      c13 = __builtin_amdgcn_mfma_f32_16x16x32_f16(Ah[1][7], B7, c13, 0, 0, 0);

      // x writeback first: independent of MFMA results, overlaps the chain tail
      if (wb) {
        f16x4 pv = { (_Float16)pre.x, (_Float16)pre.y, (_Float16)pre.z, (_Float16)pre.w };
        *(f16x4*)(xbuf[(blk + 1) & 1] + xoff) = pv;
      }

      f32x4 s0 = (c00 + c01) + (c02 + c03);
      f32x4 s1 = (c10 + c11) + (c12 + c13);
      float lo0 = (reg_sel & 1) ? s0[1] : s0[0];
      float hi0 = (reg_sel & 1) ? s0[3] : s0[2];
      float v0  = (reg_sel & 2) ? hi0 : lo0;
      float lo1 = (reg_sel & 1) ? s1[1] : s1[0];
      float hi1 = (reg_sel & 1) ? s1[3] : s1[2];
      float v1  = (reg_sel & 2) ? hi1 : lo1;
      float v   = (mt_sel ? v1 : v0) + xpv;
      float hn  = fast_tanh(v);
      if (n < 8) hdst[row_own] = (_Float16)hn;
      step_barrier();
    };

    if (nsteps == XBLK) {
      // ---- hot path: fully unrolled, everything compile-time
#pragma unroll
      for (int s = 0; s < XBLK; ++s)
        step(xr[s >> 2][s & 3], hbuf[s & 1], hbuf[(s + 1) & 1],
             (s == XBLK - 1) && havepre);
    } else {
      // ---- tail (last block of this sample): dynamic, xp from LDS
      for (int s = 0; s < nsteps; ++s)
        step(xp[row_own * XPS + s], hbuf[s & 1], hbuf[(s + 1) & 1], false);
    }
    t += nsteps;
  }

  // ---- epilogue: out[b] = h_final . W_fc + b_fc
  float v = 0.f;
  if (tid < nH) v = (float)hbuf[len & 1][tid] * Wfc[tid];
#pragma unroll
  for (int off = 32; off; off >>= 1) v += __shfl_down(v, off);
  if (l == 0) red[w] = v;
  __syncthreads();
  if (tid == 0) {
    float acc = bfc[0];
#pragma unroll
    for (int i = 0; i < THREADS / 64; ++i) acc += red[i];
    out[b] = acc;
  }
}

extern "C" void kernel_launch(void* const* d_in, const int* in_sizes, int n_in,
                              void* d_out, int out_size, void* d_ws, size_t ws_size,
                              hipStream_t stream) {
  const float* x   = (const float*)d_in[0];
  const int* lens  = (const int*)d_in[1];
  const float* Wih = (const float*)d_in[2];
  const float* Whh = (const float*)d_in[3];
  const float* bih = (const float*)d_in[4];
  const float* bhh = (const float*)d_in[5];
  const float* Wfc = (const float*)d_in[6];
  const float* bfc = (const float*)d_in[7];
  float* out = (float*)d_out;

  rnn_mfma<<<nB, THREADS, 0, stream>>>(x, lens, Wih, Whh, bih, bhh, Wfc, bfc, out);
}

// Round 9
// 984.069 us; speedup vs baseline: 1.0937x; 1.0937x over previous
//
#include <hip/hip_runtime.h>

// RNN B=256 T=2048 I=64 H=256 — one workgroup per sample, MFMA matvec recurrence.
// TERMINAL KERNEL: revert to R6, the verified session optimum (920us rocprof).
//
// Structural model (why this is the stopping point):
//   wall = 2048 serial steps x step-time; step = barrier + LDS h-round-trip
//   (~120cy) + per-SIMD MFMA issue (2 waves x 16 MFMA ~ 160cy) + tail (~70cy)
//   = 1078cy measured. Not a memory/compute roofline (MfmaUtil 25%, HBM 0.5%);
//   it is a latency floor bracketed empirically:
//   - TLP curve: 1/2/4 waves-per-SIMD = 1195/982/1150us -> 2/SIMD optimum.
//   - staggered 2-sample pipeline (R5): VGPR spill + 2x barriers = 1698us.
//   - depth-2 chains (R7): +VALU tail, zero benefit (step is issue-bound,
//     dep-limited time 104cy < issue 160cy) -> regression.
//   - asm lgkmcnt-only barrier (R7): compiler's barrier-aware scheduling
//     beats hand waitcnt; prefetch drain is once per 32-step block anyway.
//   - setprio (R3): pure overhead in lockstep-symmetric waves.
// Wins banked here: per-block xp mini-GEMM (timesteps as MFMA columns; input
// projection = 8 MFMA / 32 steps instead of 4/step), fully-unrolled 32-step
// hot block (static ds offsets/parity), lane's xp row in 8 f32x4 regs,
// kt-parity depth-4 chains, rcp-based tanh, prefetch after mini-GEMM barrier.

static constexpr int nB = 256;
static constexpr int nT = 2048;
static constexpr int nI = 64;
static constexpr int nH = 256;
static constexpr int XBLK = 32;     // timesteps of x staged/projected per block
static constexpr int XSTR = 72;     // halfword stride of an xbuf row
static constexpr int XPS  = 36;     // float stride of an xp row (144B: 16B-aligned)
static constexpr int THREADS = 512; // 8 waves; wave w owns output rows [32w,32w+32)

typedef _Float16 f16x8 __attribute__((ext_vector_type(8)));
typedef _Float16 f16x4 __attribute__((ext_vector_type(4)));
typedef float f32x4 __attribute__((ext_vector_type(4)));

__device__ __forceinline__ float fast_tanh(float x) {
  float a = fabsf(x);
  float e = __expf(-2.0f * a);           // in (0,1], never overflows
  float r = (1.0f - e) * __builtin_amdgcn_rcpf(1.0f + e);
  return copysignf(r, x);
}

__global__ __launch_bounds__(THREADS, 2)
void rnn_mfma(const float* __restrict__ x, const int* __restrict__ lengths,
              const float* __restrict__ Wih, const float* __restrict__ Whh,
              const float* __restrict__ bih, const float* __restrict__ bhh,
              const float* __restrict__ Wfc, const float* __restrict__ bfc,
              float* __restrict__ out)
{
  __shared__ __align__(16) _Float16 hbuf[2][nH];            // 1 KB
  __shared__ __align__(16) _Float16 xbuf[2][XBLK * XSTR];   // 9 KB
  __shared__ __align__(16) float xp[nH * XPS];              // 36 KB
  __shared__ float red[THREADS / 64];

  const int b   = blockIdx.x;
  const int tid = threadIdx.x;
  const int w   = tid >> 6;       // wave 0..7
  const int l   = tid & 63;
  const int q   = l >> 4;         // quad 0..3
  const int n   = l & 15;         // MFMA column lane
  const int len = lengths[b];     // in [1, nT]
  const float* xb = x + (size_t)b * nT * nI;

  // ---- preamble: pack this wave's W rows into A-fragments (f16)
  // A layout (16x16x32): lane holds A[m = lane&15][k = 8*(lane>>4) + j], j=0..7
  f16x8 Ah[2][8];   // W_hh rows 32w+16mt+n, k = 32kt+8q+j
  f16x8 Ax[2][2];   // W_ih (I=64 -> 2 k-tiles), mini-GEMM only
#pragma unroll
  for (int mt = 0; mt < 2; ++mt) {
    const int row = 32 * w + 16 * mt + n;
#pragma unroll
    for (int kt = 0; kt < 8; ++kt) {
      const float* src = Whh + row * nH + 32 * kt + 8 * q;
      f16x8 a;
#pragma unroll
      for (int j = 0; j < 8; ++j) a[j] = (_Float16)src[j];
      Ah[mt][kt] = a;
    }
#pragma unroll
    for (int kt = 0; kt < 2; ++kt) {
      const float* src = Wih + row * nI + 32 * kt + 8 * q;
      f16x8 a;
#pragma unroll
      for (int j = 0; j < 8; ++j) a[j] = (_Float16)src[j];
      Ax[mt][kt] = a;
    }
  }
  // bias in C layout: reg r <-> row 32w + 16mt + 4q + r (folded into xp)
  f32x4 biasC[2];
#pragma unroll
  for (int r = 0; r < 4; ++r) {
    const int r0 = 32 * w + 4 * q + r;
    biasC[0][r] = bih[r0] + bhh[r0];
    biasC[1][r] = bih[r0 + 16] + bhh[r0 + 16];
  }
  // column-split ownership: lanes n<8 each finish exactly one output row
  const int mt_sel  = (n >> 2) & 1;
  const int reg_sel = n & 3;
  const int row_own = 32 * w + 16 * mt_sel + 4 * q + reg_sel;

  // x staging geometry: thread writes 4 halfs at (row, col) of the block
  const int xoff = ((tid * 4) >> 6) * XSTR + ((tid * 4) & 63);

  // ---- h0 = 0; stage x block 0
  if (tid < nH) hbuf[0][tid] = (_Float16)0.f;
  {
    float4 v = *(const float4*)(xb + tid * 4);
    f16x4 pv = { (_Float16)v.x, (_Float16)v.y, (_Float16)v.z, (_Float16)v.w };
    *(f16x4*)(xbuf[0] + xoff) = pv;
  }
  __syncthreads();

  int t = 0;
  for (int blk = 0; t < len; ++blk) {
    // ---- xp mini-GEMM: xp[row][s] = bias + W_ih . x_{blk*32+s}; timesteps
    // are the MFMA columns (ct=0 -> s=n, ct=1 -> s=16+n).
    {
      const _Float16* xB = xbuf[blk & 1];
      f32x4 g00 = biasC[0], g01 = biasC[0], g10 = biasC[1], g11 = biasC[1];
#pragma unroll
      for (int kt = 0; kt < 2; ++kt) {
        f16x8 B0 = *(const f16x8*)(xB + n * XSTR + 32 * kt + 8 * q);         // ct=0
        f16x8 B1 = *(const f16x8*)(xB + (16 + n) * XSTR + 32 * kt + 8 * q);  // ct=1
        g00 = __builtin_amdgcn_mfma_f32_16x16x32_f16(Ax[0][kt], B0, g00, 0, 0, 0);
        g10 = __builtin_amdgcn_mfma_f32_16x16x32_f16(Ax[1][kt], B0, g10, 0, 0, 0);
        g01 = __builtin_amdgcn_mfma_f32_16x16x32_f16(Ax[0][kt], B1, g01, 0, 0, 0);
        g11 = __builtin_amdgcn_mfma_f32_16x16x32_f16(Ax[1][kt], B1, g11, 0, 0, 0);
      }
#pragma unroll
      for (int r = 0; r < 4; ++r) {
        const int r0 = (32 * w + 4 * q + r) * XPS;
        xp[r0 + n]                 = g00[r];
        xp[r0 + 16 * XPS + n]      = g10[r];
        xp[r0 + 16 + n]            = g01[r];
        xp[r0 + 16 * XPS + 16 + n] = g11[r];
      }
    }
    __syncthreads();

    // next-block x prefetch AFTER the barrier (drains at step 0's barrier,
    // ~500cy after issue, once per 32 steps), then xp row -> 8 f32x4 regs.
    float4 pre;
    const bool havepre = ((blk + 1) * XBLK < len);
    if (havepre)
      pre = *(const float4*)(xb + (size_t)(blk + 1) * XBLK * nI + tid * 4);

    f32x4 xr[8];
#pragma unroll
    for (int k = 0; k < 8; ++k)
      xr[k] = *(const f32x4*)(xp + row_own * XPS + 4 * k);

    const int nsteps = min(XBLK, len - blk * XBLK);

    // step body; xpv passed in (reg in hot path, LDS read in tail)
    auto step = [&](float xpv, const _Float16* hsrc, _Float16* hdst, bool wb) {
      f32x4 z = {0.f, 0.f, 0.f, 0.f};
      f32x4 p00 = z, p01 = z, p10 = z, p11 = z;  // kt-parity partials: depth 4
#pragma unroll
      for (int kt = 0; kt < 8; kt += 2) {
        f16x8 Be = *(const f16x8*)(hsrc + 32 * kt + 8 * q);
        f16x8 Bo = *(const f16x8*)(hsrc + 32 * (kt + 1) + 8 * q);
        p00 = __builtin_amdgcn_mfma_f32_16x16x32_f16(Ah[0][kt],     Be, p00, 0, 0, 0);
        p10 = __builtin_amdgcn_mfma_f32_16x16x32_f16(Ah[1][kt],     Be, p10, 0, 0, 0);
        p01 = __builtin_amdgcn_mfma_f32_16x16x32_f16(Ah[0][kt + 1], Bo, p01, 0, 0, 0);
        p11 = __builtin_amdgcn_mfma_f32_16x16x32_f16(Ah[1][kt + 1], Bo, p11, 0, 0, 0);
      }
      f32x4 s0 = p00 + p01;
      f32x4 s1 = p10 + p11;
      float lo0 = (reg_sel & 1) ? s0[1] : s0[0];
      float hi0 = (reg_sel & 1) ? s0[3] : s0[2];
      float v0  = (reg_sel & 2) ? hi0 : lo0;
      float lo1 = (reg_sel & 1) ? s1[1] : s1[0];
      float hi1 = (reg_sel & 1) ? s1[3] : s1[2];
      float v1  = (reg_sel & 2) ? hi1 : lo1;
      float v   = (mt_sel ? v1 : v0) + xpv;
      float hn  = fast_tanh(v);
      if (wb) {  // stage next x block before this block's final barrier
        f16x4 pv = { (_Float16)pre.x, (_Float16)pre.y, (_Float16)pre.z, (_Float16)pre.w };
        *(f16x4*)(xbuf[(blk + 1) & 1] + xoff) = pv;
      }
      if (n < 8) hdst[row_own] = (_Float16)hn;
      __syncthreads();
    };

    if (nsteps == XBLK) {
      // ---- hot path: fully unrolled, everything compile-time
#pragma unroll
      for (int s = 0; s < XBLK; ++s)
        step(xr[s >> 2][s & 3], hbuf[s & 1], hbuf[(s + 1) & 1],
             (s == XBLK - 1) && havepre);
    } else {
      // ---- tail (last block of this sample): dynamic, xp from LDS
      for (int s = 0; s < nsteps; ++s)
        step(xp[row_own * XPS + s], hbuf[s & 1], hbuf[(s + 1) & 1], false);
    }
    t += nsteps;
  }

  // ---- epilogue: out[b] = h_final . W_fc + b_fc
  float v = 0.f;
  if (tid < nH) v = (float)hbuf[len & 1][tid] * Wfc[tid];
#pragma unroll
  for (int off = 32; off; off >>= 1) v += __shfl_down(v, off);
  if (l == 0) red[w] = v;
  __syncthreads();
  if (tid == 0) {
    float acc = bfc[0];
#pragma unroll
    for (int i = 0; i < THREADS / 64; ++i) acc += red[i];
    out[b] = acc;
  }
}

extern "C" void kernel_launch(void* const* d_in, const int* in_sizes, int n_in,
                              void* d_out, int out_size, void* d_ws, size_t ws_size,
                              hipStream_t stream) {
  const float* x   = (const float*)d_in[0];
  const int* lens  = (const int*)d_in[1];
  const float* Wih = (const float*)d_in[2];
  const float* Whh = (const float*)d_in[3];
  const float* bih = (const float*)d_in[4];
  const float* bhh = (const float*)d_in[5];
  const float* Wfc = (const float*)d_in[6];
  const float* bfc = (const float*)d_in[7];
  float* out = (float*)d_out;

  rnn_mfma<<<nB, THREADS, 0, stream>>>(x, lens, Wih, Whh, bih, bhh, Wfc, bfc, out);
}